// Round 5
// baseline (2474.125 us; speedup 1.0000x reference)
//
#include <hip/hip_runtime.h>
#include <stdint.h>

#define B_  8
#define S_  2048
#define DM  1024
#define NI  4096
#define NP  2048
#define DR  256
#define H2  512
#define KI  2048
#define KP  1024
#define LDW 40   // legacy padded stride (gemm3 B only)

typedef __attribute__((ext_vector_type(8))) short bf16x8;
typedef __attribute__((ext_vector_type(8))) _Float16 f16x8;
typedef __attribute__((ext_vector_type(4))) float f32x4;
typedef unsigned short ushort;
typedef unsigned int uint;

__device__ __forceinline__ float gelu_erf(float v){
    return 0.5f * v * (1.0f + erff(v * 0.7071067811865476f));
}
__device__ __forceinline__ ushort f2b(float f){      // fp32 -> bf16 bits, RNE
    union { float f; uint u; } a; a.f = f;
    uint r = a.u + 0x7fffu + ((a.u >> 16) & 1u);
    return (ushort)(r >> 16);
}
__device__ __forceinline__ float b2f(ushort u){
    union { uint u; float f; } a; a.u = ((uint)u) << 16; return a.f;
}
__device__ __forceinline__ ushort f2h(float f){      // fp32 -> fp16 bits, RNE
    union { _Float16 h; ushort u; } v; v.h = (_Float16)f; return v.u;
}

// Swizzled LDS layout: row stride 32 ushorts (64B); 16B chunk c of row r goes
// to physical chunk c ^ ((r>>1)&3). Rows offset by multiples of 16 share the
// same swizzle selector -> fragment reads & tiled staging use one selector.
#define SWZ_ST(r, c)  ((r)*32 + ((((c) ^ (((r) >> 1) & 3))) << 3))

// ---------------- fp32 -> fp16 bulk convert ---------------------------------
__global__ __launch_bounds__(256) void k_cvt(const float* __restrict__ in,
                                             ushort* __restrict__ out, int n8){
    int i = blockIdx.x*256 + threadIdx.x;
    int stride = gridDim.x*256;
    for(; i < n8; i += stride){
        const float* p = in + (size_t)i*8;
        ushort h[8];
        #pragma unroll
        for(int j = 0; j < 8; j++) h[j] = f2h(p[j]);
        *(uint4*)(out + (size_t)i*8) = *(uint4*)h;
    }
}

// ---------------- Router (all fp32) -----------------------------------------
__global__ __launch_bounds__(256) void k_gpart(const float* __restrict__ x,
                                               float* __restrict__ gpart){
    int b = blockIdx.x >> 4, ch = blockIdx.x & 15;
    const float4* xb = (const float4*)(x + ((size_t)b*S_ + (size_t)ch*128) * DM);
    int t = threadIdx.x;
    float4 m = xb[t];
    for(int r = 1; r < 128; r++){
        float4 v = xb[(size_t)r*(DM/4) + t];
        m.x = fmaxf(m.x, v.x); m.y = fmaxf(m.y, v.y);
        m.z = fmaxf(m.z, v.z); m.w = fmaxf(m.w, v.w);
    }
    ((float4*)(gpart + (size_t)(b*16 + ch)*DM))[t] = m;
}

__global__ __launch_bounds__(256) void k_h(const float* __restrict__ gpart,
                                           const float* __restrict__ W1,
                                           const float* __restrict__ b1,
                                           float* __restrict__ h){
    __shared__ float g[DM];
    int b = blockIdx.x >> 3, ig = blockIdx.x & 7;
    int t = threadIdx.x;
    for(int d = t; d < DM; d += 256){
        float m = gpart[(size_t)(b*16)*DM + d];
        for(int c = 1; c < 16; c++) m = fmaxf(m, gpart[(size_t)(b*16 + c)*DM + d]);
        g[d] = m;
    }
    __syncthreads();
    int i  = ig*64 + (t >> 2);
    int dq = (t & 3) * 256;
    const float* wr = W1 + (size_t)i*DM + dq;
    const float* gg = g + dq;
    float s = 0.f;
    for(int d = 0; d < 256; d++) s = fmaf(gg[d], wr[d], s);
    s += __shfl_xor(s, 1);
    s += __shfl_xor(s, 2);
    if((t & 3) == 0) h[b*H2 + i] = gelu_erf(s + b1[i]);
}

__global__ __launch_bounds__(256) void k_query(const float* __restrict__ h,
                                               const float* __restrict__ lng,
                                               const float* __restrict__ lnb,
                                               const float* __restrict__ W2,
                                               const float* __restrict__ b2,
                                               float* __restrict__ query){
    __shared__ float hn[H2];
    __shared__ float red[4];
    int b = blockIdx.x >> 2, qg = blockIdx.x & 3;
    int t = threadIdx.x;
    float v0 = h[b*H2 + t], v1 = h[b*H2 + 256 + t];
    float s = v0 + v1;
    for(int o = 32; o > 0; o >>= 1) s += __shfl_down(s, o);
    if((t & 63) == 0) red[t >> 6] = s;
    __syncthreads();
    float mean = (red[0] + red[1] + red[2] + red[3]) * (1.f/H2);
    __syncthreads();
    float d0 = v0 - mean, d1 = v1 - mean;
    float sq = d0*d0 + d1*d1;
    for(int o = 32; o > 0; o >>= 1) sq += __shfl_down(sq, o);
    if((t & 63) == 0) red[t >> 6] = sq;
    __syncthreads();
    float var  = (red[0] + red[1] + red[2] + red[3]) * (1.f/H2);
    float rstd = rsqrtf(var + 1e-5f);
    hn[t]       = d0*rstd*lng[t]       + lnb[t];
    hn[256 + t] = d1*rstd*lng[256 + t] + lnb[256 + t];
    __syncthreads();
    int q  = qg*64 + (t >> 2);
    int iq = (t & 3) * 128;
    const float* wr = W2 + (size_t)q*H2 + iq;
    float acc = 0.f;
    for(int i2 = 0; i2 < 128; i2++) acc = fmaf(hn[iq + i2], wr[i2], acc);
    acc += __shfl_xor(acc, 1);
    acc += __shfl_xor(acc, 2);
    if((t & 3) == 0) query[b*DR + q] = acc + b2[q];
}

__global__ __launch_bounds__(256) void k_logits(const float* __restrict__ query,
                                                const float* __restrict__ nk,
                                                float* __restrict__ logits){
    __shared__ float q[DR];
    int b = blockIdx.x >> 4, ng = blockIdx.x & 15;
    int t = threadIdx.x;
    if(t < DR) q[t] = query[b*DR + t];
    __syncthreads();
    int n = ng*256 + t;
    const float* kr = nk + (size_t)n*DR;
    float s = 0.f;
    for(int i = 0; i < DR; i++) s = fmaf(q[i], kr[i], s);
    logits[b*NI + n] = s * 0.0625f;
}

// ------- Top-k SET selection, SORTED ascending output (scan-based) ----------
template<int N_, int KSEL>
__global__ __launch_bounds__(256) void k_topk(const float* __restrict__ vals,
                                              int* __restrict__ idxout){
    __shared__ unsigned u[N_];
    __shared__ int redc[4];
    __shared__ int sc[256];
    int t = threadIdx.x;
    size_t vbase = (size_t)blockIdx.x * N_;
    size_t obase = (size_t)blockIdx.x * KSEL;
    for(int i = t; i < N_; i += 256){
        unsigned bits = __float_as_uint(vals[vbase + i]);
        u[i] = (bits & 0x80000000u) ? ~bits : (bits | 0x80000000u);
    }
    __syncthreads();
    unsigned lo = 0u, hi = 0xFFFFFFFFu;
    while(lo < hi){
        unsigned mid = lo + (unsigned)((((unsigned long long)(hi - lo)) + 1ull) >> 1);
        int c = 0;
        for(int i = t; i < N_; i += 256) c += (u[i] >= mid) ? 1 : 0;
        for(int o = 32; o > 0; o >>= 1) c += __shfl_down(c, o);
        if((t & 63) == 0) redc[t >> 6] = c;
        __syncthreads();
        int tot = redc[0] + redc[1] + redc[2] + redc[3];
        if(tot >= KSEL) lo = mid; else hi = mid - 1;
        __syncthreads();
    }
    unsigned T = lo;
    const int PER = N_ / 256;
    int base = t * PER;
    int lgt = 0, leq = 0;
    for(int j = 0; j < PER; j++){
        unsigned v = u[base + j];
        lgt += (v > T) ? 1 : 0; leq += (v == T) ? 1 : 0;
    }
    sc[t] = (lgt << 16) | leq;
    __syncthreads();
    for(int o = 1; o < 256; o <<= 1){
        int add = (t >= o) ? sc[t - o] : 0;
        __syncthreads();
        sc[t] += add;
        __syncthreads();
    }
    int need = KSEL - (sc[255] >> 16);
    int ex = (t == 0) ? 0 : sc[t - 1];
    int pos = (ex >> 16) + ((ex & 0xffff) < need ? (ex & 0xffff) : need);
    int eq = ex & 0xffff;
    for(int j = 0; j < PER; j++){
        unsigned v = u[base + j];
        if(v > T){ idxout[obase + pos++] = base + j; }
        else if(v == T){ if(eq < need){ idxout[obase + pos++] = base + j; } eq++; }
    }
}

// ------- GEMM1 (G batches): selin = gelu(x16_b @ patt16[iidx]^T), 1-pass f16.
// Output stored as split bf16 (hi+lo) for gemm2's 3-pass path.
__global__ __launch_bounds__(256) void k_gemm1(const ushort* __restrict__ x16,
                                               const ushort* __restrict__ patt16,
                                               const int* __restrict__ iidx,
                                               ushort* __restrict__ selh,
                                               ushort* __restrict__ sell, int b0){
    __shared__ __align__(16) ushort As[128*32], Bs[128*32];
    __shared__ int rowmap[128];
    int t = threadIdx.x;
    int g = blockIdx.x >> 8, rest = blockIdx.x & 255;
    int b = b0 + g;
    int mb = rest >> 4, nb = rest & 15;
    int m0 = mb*128, n0 = nb*128;
    ushort* selh_g = selh + (size_t)g*S_*KI;
    ushort* sell_g = sell + (size_t)g*S_*KI;
    if(t < 128) rowmap[t] = iidx[(size_t)b*KI + n0 + t];
    __syncthreads();
    int c = t & 3, r2 = t >> 2;          // rows r2 and r2+64, 16B chunk c
    const ushort* a0p = x16 + (size_t)b*S_*DM + (size_t)(m0 + r2)*DM + c*8;
    const ushort* a1p = a0p + (size_t)64*DM;
    const ushort* b0p = patt16 + (size_t)rowmap[r2]*DM + c*8;
    const ushort* b1p = patt16 + (size_t)rowmap[r2 + 64]*DM + c*8;
    uint4 A0 = *(const uint4*)a0p, A1 = *(const uint4*)a1p;
    uint4 B0 = *(const uint4*)b0p, B1 = *(const uint4*)b1p;
    int st0 = SWZ_ST(r2, c);
    int st1 = st0 + 64*32;               // (r2+64) has same swizzle selector
    int w = t >> 6, lane = t & 63;
    int mbase = (w >> 1)*64, nbase = (w & 1)*64;
    int lm = lane & 15, q = lane >> 4;
    int fq = ((q ^ ((lm >> 1) & 3)) << 3);
    f32x4 acc[4][4];
    #pragma unroll
    for(int i = 0; i < 4; i++)
      #pragma unroll
      for(int j = 0; j < 4; j++) acc[i][j] = f32x4{0.f,0.f,0.f,0.f};
    for(int k0 = 0; k0 < DM; k0 += 32){
        __syncthreads();
        *(uint4*)(As + st0) = A0; *(uint4*)(As + st1) = A1;
        *(uint4*)(Bs + st0) = B0; *(uint4*)(Bs + st1) = B1;
        __syncthreads();
        if(k0 + 32 < DM){
            a0p += 32; a1p += 32; b0p += 32; b1p += 32;
            A0 = *(const uint4*)a0p; A1 = *(const uint4*)a1p;
            B0 = *(const uint4*)b0p; B1 = *(const uint4*)b1p;
        }
        f16x8 af[4], bf[4];
        #pragma unroll
        for(int mt = 0; mt < 4; mt++)
            af[mt] = *(const f16x8*)(As + (mbase + mt*16 + lm)*32 + fq);
        #pragma unroll
        for(int nt = 0; nt < 4; nt++)
            bf[nt] = *(const f16x8*)(Bs + (nbase + nt*16 + lm)*32 + fq);
        #pragma unroll
        for(int nt = 0; nt < 4; nt++)
          #pragma unroll
          for(int mt = 0; mt < 4; mt++)
            acc[mt][nt] = __builtin_amdgcn_mfma_f32_16x16x32_f16(af[mt], bf[nt], acc[mt][nt], 0, 0, 0);
    }
    #pragma unroll
    for(int mt = 0; mt < 4; mt++)
      #pragma unroll
      for(int nt = 0; nt < 4; nt++){
        int col = n0 + nbase + nt*16 + lm;
        #pragma unroll
        for(int i = 0; i < 4; i++){
            int row = m0 + mbase + mt*16 + q*4 + i;
            float gv = gelu_erf(acc[mt][nt][i]);
            ushort hbits = f2b(gv);
            selh_g[(size_t)row*KI + col] = hbits;
            sell_g[(size_t)row*KI + col] = f2b(gv - b2f(hbits));
        }
      }
}

// ------- Gather (G batches): split pw columns -> wh/wl; zero scores ---------
__global__ __launch_bounds__(256) void k_gather_wsel(const float* __restrict__ pw,
                                                     const int* __restrict__ iidx,
                                                     ushort* __restrict__ wh,
                                                     ushort* __restrict__ wl,
                                                     float* __restrict__ scores, int b0){
    __shared__ int kidx[KI];
    int g = blockIdx.x >> 8, pc = blockIdx.x & 255;
    int b = b0 + g;
    ushort* wh_g = wh + (size_t)g*NP*KI;
    ushort* wl_g = wl + (size_t)g*NP*KI;
    int t = threadIdx.x;
    for(int i = t; i < KI; i += 256) kidx[i] = iidx[(size_t)b*KI + i];
    if(t < 8) scores[(size_t)b*NP + pc*8 + t] = 0.f;
    __syncthreads();
    for(int r2 = 0; r2 < 8; r2++){
        int p = pc*8 + r2;
        const float* row = pw + (size_t)p*NI;
        for(int j = t; j < KI; j += 256){
            float v = row[kidx[j]];                 // kidx sorted -> good locality
            ushort hb = f2b(v);
            wh_g[(size_t)p*KI + j] = hb;
            wl_g[(size_t)p*KI + j] = f2b(v - b2f(hb));
        }
    }
}

// ------- GEMM2 (G batches): acts=gelu(selin @ wsel^T) 3-pass split-bf16 -----
__global__ __launch_bounds__(256) void k_gemm2(const ushort* __restrict__ selh,
                                               const ushort* __restrict__ sell,
                                               const ushort* __restrict__ wh,
                                               const ushort* __restrict__ wl,
                                               ushort* __restrict__ acts,
                                               float* __restrict__ scores, int b0){
    __shared__ __align__(16) ushort P0[128*32], P1[128*32], P2[128*32], P3[128*32];
    __shared__ float colsum[128];
    int t = threadIdx.x;
    int g = blockIdx.x >> 8, rest = blockIdx.x & 255;
    int b = b0 + g;
    int mb = rest >> 4, nb = rest & 15;
    int m0 = mb*128, n0 = nb*128;
    const ushort* selh_g = selh + (size_t)g*S_*KI;
    const ushort* sell_g = sell + (size_t)g*S_*KI;
    const ushort* wh_g   = wh   + (size_t)g*NP*KI;
    const ushort* wl_g   = wl   + (size_t)g*NP*KI;
    ushort* acts_g = acts + (size_t)g*S_*NP;
    int w = t >> 6, lane = t & 63;
    // staging: wave w owns plane w; lane covers rows r2+16j (j=0..7), chunk c
    int c = lane & 3, r2 = lane >> 2;
    const ushort* gp = (w == 0) ? (selh_g + (size_t)m0*KI) :
                       (w == 1) ? (sell_g + (size_t)m0*KI) :
                       (w == 2) ? (wh_g   + (size_t)n0*KI) :
                                  (wl_g   + (size_t)n0*KI);
    gp += (size_t)r2*KI + c*8;
    ushort* Pw = (w == 0) ? P0 : (w == 1) ? P1 : (w == 2) ? P2 : P3;
    uint4 V[8];
    #pragma unroll
    for(int j = 0; j < 8; j++) V[j] = *(const uint4*)(gp + (size_t)(16*j)*KI);
    int stb = SWZ_ST(r2, c);             // rows r2+16j share the selector
    int mbase = (w >> 1)*64, nbase = (w & 1)*64;
    int lm = lane & 15, q = lane >> 4;
    int fq = ((q ^ ((lm >> 1) & 3)) << 3);
    f32x4 acc[4][4];
    #pragma unroll
    for(int i = 0; i < 4; i++)
      #pragma unroll
      for(int j = 0; j < 4; j++) acc[i][j] = f32x4{0.f,0.f,0.f,0.f};
    for(int k0 = 0; k0 < KI; k0 += 32){
        __syncthreads();
        #pragma unroll
        for(int j = 0; j < 8; j++) *(uint4*)(Pw + stb + j*16*32) = V[j];
        __syncthreads();
        if(k0 + 32 < KI){
            gp += 32;
            #pragma unroll
            for(int j = 0; j < 8; j++) V[j] = *(const uint4*)(gp + (size_t)(16*j)*KI);
        }
        bf16x8 ahf[4], alf[4];
        #pragma unroll
        for(int mt = 0; mt < 4; mt++){
            int ro = (mbase + mt*16 + lm)*32 + fq;
            ahf[mt] = *(const bf16x8*)(P0 + ro);
            alf[mt] = *(const bf16x8*)(P1 + ro);
        }
        #pragma unroll
        for(int nt = 0; nt < 4; nt++){
            int ro = (nbase + nt*16 + lm)*32 + fq;
            bf16x8 bhf = *(const bf16x8*)(P2 + ro);
            bf16x8 blf = *(const bf16x8*)(P3 + ro);
            #pragma unroll
            for(int mt = 0; mt < 4; mt++){
                acc[mt][nt] = __builtin_amdgcn_mfma_f32_16x16x32_bf16(ahf[mt], bhf, acc[mt][nt], 0, 0, 0);
                acc[mt][nt] = __builtin_amdgcn_mfma_f32_16x16x32_bf16(ahf[mt], blf, acc[mt][nt], 0, 0, 0);
                acc[mt][nt] = __builtin_amdgcn_mfma_f32_16x16x32_bf16(alf[mt], bhf, acc[mt][nt], 0, 0, 0);
            }
        }
    }
    if(t < 128) colsum[t] = 0.f;
    __syncthreads();
    #pragma unroll
    for(int mt = 0; mt < 4; mt++)
      #pragma unroll
      for(int nt = 0; nt < 4; nt++){
        int cb = nbase + nt*16 + lm;
        float s4 = 0.f;
        #pragma unroll
        for(int i = 0; i < 4; i++){
            int row = m0 + mbase + mt*16 + q*4 + i;
            float gv = gelu_erf(acc[mt][nt][i]);
            s4 += gv;
            acts_g[(size_t)row*NP + n0 + cb] = f2h(gv);   // acts now fp16
        }
        atomicAdd(&colsum[cb], s4);
      }
    __syncthreads();
    if(t < 128) atomicAdd(&scores[(size_t)b*NP + n0 + t], colsum[t]);
}

// ------- Gather (G batches): selacts[s][j] = acts[s][pix[j]] (fp16 bits) ----
__global__ __launch_bounds__(256) void k_gather_selacts(const ushort* __restrict__ acts,
                                                        const int* __restrict__ pidx,
                                                        ushort* __restrict__ selacts, int b0){
    __shared__ int pix[KP];
    int g = blockIdx.x >> 6, sc_ = blockIdx.x & 63;
    int b = b0 + g;
    const ushort* acts_g = acts + (size_t)g*S_*NP;
    ushort* selacts_g = selacts + (size_t)g*S_*KP;
    int t = threadIdx.x;
    for(int i = t; i < KP; i += 256) pix[i] = pidx[(size_t)b*KP + i];
    __syncthreads();
    const ushort* Ab = acts_g    + ((size_t)sc_*32)*NP;
    ushort*       Ob = selacts_g + ((size_t)sc_*32)*KP;
    for(int r2 = 0; r2 < 32; r2++){
        for(int j = t; j < KP; j += 256)
            Ob[(size_t)r2*KP + j] = Ab[(size_t)r2*NP + pix[j]];
    }
}

// ------- GEMM3 (G batches): out_b = selacts(f16) @ pout[pix] (1-pass f16) ---
__global__ __launch_bounds__(256) void k_gemm3(const ushort* __restrict__ selacts,
                                               const float* __restrict__ pout,
                                               const int* __restrict__ pidx,
                                               float* __restrict__ out, int b0){
    __shared__ __align__(16) ushort As[128*32];      // A: swizzled fp16
    __shared__ __align__(16) ushort Bs[128*LDW];     // B: padded linear fp16
    __shared__ int pix[KP];
    int t = threadIdx.x;
    int g = blockIdx.x >> 7, rest = blockIdx.x & 127;
    int b = b0 + g;
    int mb = rest >> 3, nb = rest & 7;
    int m0 = mb*128, n0 = nb*128;
    const ushort* selacts_g = selacts + (size_t)g*S_*KP;
    for(int i = t; i < KP; i += 256) pix[i] = pidx[(size_t)b*KP + i];
    __syncthreads();
    int c = t & 3, r2 = t >> 2;
    const ushort* a0p = selacts_g + (size_t)(m0 + r2)*KP + c*8;
    const ushort* a1p = a0p + (size_t)64*KP;
    uint4 A0 = *(const uint4*)a0p, A1 = *(const uint4*)a1p;
    int st0 = SWZ_ST(r2, c);
    int st1 = st0 + 64*32;
    int kk = t >> 3, nc = (t & 7)*16;                // B: 32 k-rows x 128 n-cols
    float4 fb[4];
    {
        const float* bg = pout + (size_t)pix[kk]*DM + n0 + nc;
        #pragma unroll
        for(int i = 0; i < 4; i++) fb[i] = *(const float4*)(bg + i*4);
    }
    int w = t >> 6, lane = t & 63;
    int mbase = (w >> 1)*64, nbase = (w & 1)*64;
    int lm = lane & 15, q = lane >> 4;
    int fq = ((q ^ ((lm >> 1) & 3)) << 3);
    f32x4 acc[4][4];
    #pragma unroll
    for(int i = 0; i < 4; i++)
      #pragma unroll
      for(int j = 0; j < 4; j++) acc[i][j] = f32x4{0.f,0.f,0.f,0.f};
    for(int k0 = 0; k0 < KP; k0 += 32){
        __syncthreads();
        *(uint4*)(As + st0) = A0;
        *(uint4*)(As + st1) = A1;
        {
            const float* pf = (const float*)fb;
            #pragma unroll
            for(int c2 = 0; c2 < 16; c2++) Bs[(nc + c2)*LDW + kk] = f2h(pf[c2]);
        }
        __syncthreads();
        if(k0 + 32 < KP){
            a0p += 32; a1p += 32;
            A0 = *(const uint4*)a0p; A1 = *(const uint4*)a1p;
            const float* bg = pout + (size_t)pix[k0 + 32 + kk]*DM + n0 + nc;
            #pragma unroll
            for(int i = 0; i < 4; i++) fb[i] = *(const float4*)(bg + i*4);
        }
        f16x8 af[4];
        #pragma unroll
        for(int mt = 0; mt < 4; mt++)
            af[mt] = *(const f16x8*)(As + (mbase + mt*16 + lm)*32 + fq);
        #pragma unroll
        for(int nt = 0; nt < 4; nt++){
            f16x8 bf = *(const f16x8*)(Bs + (nbase + nt*16 + lm)*LDW + q*8);
            #pragma unroll
            for(int mt = 0; mt < 4; mt++)
                acc[mt][nt] = __builtin_amdgcn_mfma_f32_16x16x32_f16(af[mt], bf, acc[mt][nt], 0, 0, 0);
        }
    }
    float* Cb = out + (size_t)b*S_*DM;
    #pragma unroll
    for(int mt = 0; mt < 4; mt++)
      #pragma unroll
      for(int nt = 0; nt < 4; nt++){
        int col = n0 + nbase + nt*16 + lm;
        #pragma unroll
        for(int i = 0; i < 4; i++){
            int row = m0 + mbase + mt*16 + q*4 + i;
            Cb[(size_t)row*DM + col] = acc[mt][nt][i];
        }
      }
}

// ---------------- launch ----------------------------------------------------
extern "C" void kernel_launch(void* const* d_in, const int* in_sizes, int n_in,
                              void* d_out, int out_size, void* d_ws, size_t ws_size,
                              hipStream_t stream){
    const float* x    = (const float*)d_in[0];
    const float* W1   = (const float*)d_in[3];
    const float* b1   = (const float*)d_in[4];
    const float* lng  = (const float*)d_in[5];
    const float* lnb  = (const float*)d_in[6];
    const float* W2   = (const float*)d_in[7];
    const float* b2   = (const float*)d_in[8];
    const float* nk   = (const float*)d_in[9];
    const float* patt = (const float*)d_in[10];
    const float* pw   = (const float*)d_in[11];
    const float* pout = (const float*)d_in[12];
    float* out = (float*)d_out;

    const size_t A256 = 255;
    auto rnd = [&](size_t v){ return (v + A256) & ~A256; };
    const size_t fixed = rnd((size_t)B_*16*DM*4) + rnd((size_t)B_*H2*4) +
                         rnd((size_t)B_*DR*4) + rnd((size_t)B_*NI*4) +
                         rnd((size_t)B_*KI*4) + rnd((size_t)B_*NP*4) +
                         rnd((size_t)B_*KP*4) +
                         rnd((size_t)B_*S_*DM*2) + rnd((size_t)NI*DM*2);  // x16, patt16
    const size_t perb = rnd((size_t)S_*KI*2) * 2 + rnd((size_t)NP*KI*2) * 2 +
                        rnd((size_t)S_*NP*2) + rnd((size_t)S_*KP*2);
    int G = 4;                                   // constant per ws_size -> capture-safe
    while(G > 1 && fixed + (size_t)G*perb > ws_size) G >>= 1;
    if(fixed + (size_t)G*perb > ws_size) return; // clean-fail guard

    char* wsp = (char*)d_ws;
    size_t off = 0;
    auto alloc = [&](size_t bytes) -> void* {
        void* p = wsp + off;
        off += rnd(bytes);
        return p;
    };
    float*  gpart   = (float*) alloc((size_t)B_*16*DM*4);
    float*  h       = (float*) alloc((size_t)B_*H2*4);
    float*  query   = (float*) alloc((size_t)B_*DR*4);
    float*  logits  = (float*) alloc((size_t)B_*NI*4);
    int*    iidx    = (int*)   alloc((size_t)B_*KI*4);
    float*  scores  = (float*) alloc((size_t)B_*NP*4);
    int*    pidx    = (int*)   alloc((size_t)B_*KP*4);
    ushort* x16     = (ushort*)alloc((size_t)B_*S_*DM*2);  // 33.5 MB
    ushort* patt16  = (ushort*)alloc((size_t)NI*DM*2);     //  8.4 MB
    ushort* selh    = (ushort*)alloc((size_t)G*S_*KI*2);
    ushort* sell    = (ushort*)alloc((size_t)G*S_*KI*2);
    ushort* wselh   = (ushort*)alloc((size_t)G*NP*KI*2);
    ushort* wsell   = (ushort*)alloc((size_t)G*NP*KI*2);
    ushort* acts    = (ushort*)alloc((size_t)G*S_*NP*2);
    ushort* selacts = (ushort*)alloc((size_t)G*S_*KP*2);

    dim3 blk(256);
    k_cvt   <<<2048, blk, 0, stream>>>(x, x16, (int)((size_t)B_*S_*DM/8));
    k_cvt   <<<1024, blk, 0, stream>>>(patt, patt16, (int)((size_t)NI*DM/8));
    k_gpart <<<128, blk, 0, stream>>>(x, gpart);
    k_h     <<<64,  blk, 0, stream>>>(gpart, W1, b1, h);
    k_query <<<32,  blk, 0, stream>>>(h, lng, lnb, W2, b2, query);
    k_logits<<<128, blk, 0, stream>>>(query, nk, logits);
    k_topk<NI, KI><<<B_, blk, 0, stream>>>(logits, iidx);
    for(int b0 = 0; b0 < B_; b0 += G){
        k_gemm1        <<<G*256, blk, 0, stream>>>(x16, patt16, iidx, selh, sell, b0);
        k_gather_wsel  <<<G*256, blk, 0, stream>>>(pw, iidx, wselh, wsell, scores, b0);
        k_gemm2        <<<G*256, blk, 0, stream>>>(selh, sell, wselh, wsell, acts, scores, b0);
        k_topk<NP, KP> <<<G,     blk, 0, stream>>>(scores + (size_t)b0*NP, pidx + (size_t)b0*KP);
        k_gather_selacts<<<G*64, blk, 0, stream>>>(acts, pidx, selacts, b0);
        k_gemm3        <<<G*128, blk, 0, stream>>>(selacts, pout, pidx, out, b0);
    }
}